// Round 12
// baseline (118.995 us; speedup 1.0000x reference)
//
#include <hip/hip_runtime.h>
#include <math.h>

// SinkhornWarpInterpolator, v3: 1 window per block, 3 blocks/CU occupancy.
// 1024 blocks x 256 threads. LDS = f0+f1 (token-major, 37.9KB); M reuses f0.
// GEMM: M = A.B^T with both operands token-major (4x4 acc/thread).
// Sinkhorn: owner wave (blk&3) holds K rows + K^T rows in 128 VGPRs,
// factored updates u=1/(Kv), v=1/(K^T u) with readlane broadcast.

#define S0 68   // LDS row stride in floats (16B aligned, bank-spreading)

__device__ __forceinline__ float rlane(float v, int l) {
    return __uint_as_float(__builtin_amdgcn_readlane(__float_as_uint(v), l));
}

__global__ __launch_bounds__(256, 3)
void skw_kernel(const float* __restrict__ z0, const float* __restrict__ z1,
                float* __restrict__ out) {
    __shared__ float f0[64 * S0];         // z0 tokens; reused as M after GEMM
    __shared__ float f1[64 * S0];         // z1 tokens (token-major now)
    __shared__ float psq0[256], psq1[256];
    __shared__ float invn0[64], invn1[64];
    __shared__ float dispx[64], dispy[64];

    const int t   = threadIdx.x;
    const int blk = blockIdx.x;            // 1024 = b(16) x wy(8) x wx(8)
    const int b   = blk >> 6;
    const int wy  = (blk >> 3) & 7;
    const int wx  = blk & 7;
    const int Y0  = wy * 32, X0 = wx * 32;

    const int xq = t & 7;                  // float4 column within 32 px
    const int yy = (t >> 3) & 31;          // pixel row within window
    const int mm = (yy >> 2) * 8 + xq;     // token index
    const int pi = yy & 3;                 // row within patch

    // ---- stage z0,z1 -> f0,f1 (token-major) + per-thread sumsq ----
    {
        const size_t base = (size_t)(b * 4) * 65536 + (size_t)(Y0 + yy) * 256 + X0 + xq * 4;
        const float* s0p = z0 + base;
        const float* s1p = z1 + base;
        float a0 = 0.f, a1 = 0.f;
        #pragma unroll
        for (int c = 0; c < 4; ++c) {
            float4 v0 = *(const float4*)(s0p + c * 65536);
            float4 v1 = *(const float4*)(s1p + c * 65536);
            a0 += v0.x*v0.x + v0.y*v0.y + v0.z*v0.z + v0.w*v0.w;
            a1 += v1.x*v1.x + v1.y*v1.y + v1.z*v1.z + v1.w*v1.w;
            *(float4*)&f0[mm * S0 + c * 16 + pi * 4] = v0;
            *(float4*)&f1[mm * S0 + c * 16 + pi * 4] = v1;
        }
        psq0[t] = a0; psq1[t] = a1;
    }
    __syncthreads();
    if (t < 128) {
        const int u2 = t & 63;
        const float* ps = (t < 64) ? psq0 : psq1;
        const int ti = u2 >> 3, tj = u2 & 7;
        float s = ps[(ti*4+0)*8+tj] + ps[(ti*4+1)*8+tj]
                + ps[(ti*4+2)*8+tj] + ps[(ti*4+3)*8+tj];
        float r = 1.0f / fmaxf(sqrtf(s), 1e-6f);
        if (t < 64) invn0[u2] = r; else invn1[u2] = r;
    }
    __syncthreads();

    // ---- GEMM: acc[r][s] = dot(f0 row bi*4+r, f1 row bj*4+s) ----
    const int bi = t >> 4, bj = t & 15;
    float acc[4][4];
    #pragma unroll
    for (int r = 0; r < 4; ++r)
        #pragma unroll
        for (int s2 = 0; s2 < 4; ++s2) acc[r][s2] = 0.f;

    #pragma unroll 4
    for (int dc = 0; dc < 16; ++dc) {
        float4 A[4], Bv[4];
        #pragma unroll
        for (int r = 0; r < 4; ++r)  A[r]  = *(const float4*)&f0[(bi*4+r)*S0 + dc*4];
        #pragma unroll
        for (int s2 = 0; s2 < 4; ++s2) Bv[s2] = *(const float4*)&f1[(bj*4+s2)*S0 + dc*4];
        #pragma unroll
        for (int r = 0; r < 4; ++r)
            #pragma unroll
            for (int s2 = 0; s2 < 4; ++s2)
                acc[r][s2] += A[r].x*Bv[s2].x + A[r].y*Bv[s2].y
                            + A[r].z*Bv[s2].z + A[r].w*Bv[s2].w;
    }
    float si[4], sj[4];
    #pragma unroll
    for (int r = 0; r < 4; ++r)  si[r] = invn0[bi*4+r] * 20.0f;   // 1/TAU
    #pragma unroll
    for (int s2 = 0; s2 < 4; ++s2) sj[s2] = invn1[bj*4+s2];
    __syncthreads();               // everyone done reading f0/f1
    float* Mm = f0;                // reuse f0 as the logits matrix
    #pragma unroll
    for (int r = 0; r < 4; ++r) {
        float4 o;
        o.x = acc[r][0]*si[r]*sj[0];
        o.y = acc[r][1]*si[r]*sj[1];
        o.z = acc[r][2]*si[r]*sj[2];
        o.w = acc[r][3]*si[r]*sj[3];
        *(float4*)&Mm[(bi*4+r)*S0 + bj*4] = o;
    }
    __syncthreads();

    // ---- owner wave: K/KT load + factored Sinkhorn, all-register ----
    const int lane = t & 63;
    if ((t >> 6) == (blk & 3)) {           // spread owner waves across SIMDs
        float K[64], KT[64];
        #pragma unroll
        for (int j4 = 0; j4 < 16; ++j4) {
            float4 r4 = *(const float4*)&Mm[lane * S0 + j4 * 4];
            K[4*j4+0] = __expf(r4.x); K[4*j4+1] = __expf(r4.y);
            K[4*j4+2] = __expf(r4.z); K[4*j4+3] = __expf(r4.w);
        }
        #pragma unroll
        for (int j = 0; j < 64; ++j) KT[j] = __expf(Mm[j * S0 + lane]);

        float u, v;
        {
            float s0=0.f, s1=0.f, s2=0.f, s3=0.f;        // R-update #1 (v==1)
            #pragma unroll
            for (int j = 0; j < 64; j += 4) {
                s0 += K[j]; s1 += K[j+1]; s2 += K[j+2]; s3 += K[j+3];
            }
            u = 1.0f / ((s0+s1) + (s2+s3));
        }
        #pragma unroll 1
        for (int it = 0; it < 19; ++it) {
            float s0=0.f, s1=0.f, s2=0.f, s3=0.f;        // C-update
            #pragma unroll
            for (int j = 0; j < 64; j += 4) {
                s0 = fmaf(KT[j  ], rlane(u, j  ), s0);
                s1 = fmaf(KT[j+1], rlane(u, j+1), s1);
                s2 = fmaf(KT[j+2], rlane(u, j+2), s2);
                s3 = fmaf(KT[j+3], rlane(u, j+3), s3);
            }
            v = 1.0f / ((s0+s1) + (s2+s3));
            s0=0.f; s1=0.f; s2=0.f; s3=0.f;              // R-update
            #pragma unroll
            for (int j = 0; j < 64; j += 4) {
                s0 = fmaf(K[j  ], rlane(v, j  ), s0);
                s1 = fmaf(K[j+1], rlane(v, j+1), s1);
                s2 = fmaf(K[j+2], rlane(v, j+2), s2);
                s3 = fmaf(K[j+3], rlane(v, j+3), s3);
            }
            u = 1.0f / ((s0+s1) + (s2+s3));
        }
        {
            float s0=0.f, s1=0.f, s2=0.f, s3=0.f;        // C-update #20
            #pragma unroll
            for (int j = 0; j < 64; j += 4) {
                s0 = fmaf(KT[j  ], rlane(u, j  ), s0);
                s1 = fmaf(KT[j+1], rlane(u, j+1), s1);
                s2 = fmaf(KT[j+2], rlane(u, j+2), s2);
                s3 = fmaf(KT[j+3], rlane(u, j+3), s3);
            }
            v = 1.0f / ((s0+s1) + (s2+s3));
        }
        // final row softmax + expected position (u cancels)
        {
            float ss=0.f, sx=0.f, sy=0.f;
            #pragma unroll
            for (int j = 0; j < 64; ++j) {
                float pj = K[j] * rlane(v, j);
                ss += pj;
                sx = fmaf(pj, (float)(j & 7),  sx);
                sy = fmaf(pj, (float)(j >> 3), sy);
            }
            const float inv = 1.0f / ss;
            dispx[lane] = sx * inv - (float)(lane & 7);
            dispy[lane] = sy * inv - (float)(lane >> 3);
        }
    }
    __syncthreads();

    // ---- warp: bilinear border sample of z1 at (pos + 4*disp) ----
    #pragma unroll
    for (int rep = 0; rep < 4; ++rep) {
        const int p = rep * 256 + t;
        const int y = p >> 5, x = p & 31;
        const int m2 = (y >> 2) * 8 + (x >> 2);
        float gx = (float)(X0 + x) + 4.0f * dispx[m2];
        float gy = (float)(Y0 + y) + 4.0f * dispy[m2];
        gx = fminf(fmaxf(gx, 0.0f), 255.0f);
        gy = fminf(fmaxf(gy, 0.0f), 255.0f);
        const float x0f = floorf(gx), y0f = floorf(gy);
        const float wxf = gx - x0f, wyf = gy - y0f;
        const int xi0 = (int)x0f, yi0 = (int)y0f;
        const int xi1 = min(xi0 + 1, 255), yi1 = min(yi0 + 1, 255);
        const float w00 = (1.f-wxf)*(1.f-wyf), w01 = wxf*(1.f-wyf);
        const float w10 = (1.f-wxf)*wyf,       w11 = wxf*wyf;
        const float* basep = z1 + (size_t)(b * 4) * 65536;
        #pragma unroll
        for (int c = 0; c < 4; ++c) {
            const float* pc = basep + c * 65536;
            const float v00 = pc[yi0*256 + xi0], v01 = pc[yi0*256 + xi1];
            const float v10 = pc[yi1*256 + xi0], v11 = pc[yi1*256 + xi1];
            out[((size_t)(b*4+c)*256 + (Y0+y))*256 + X0 + x]
                = v00*w00 + v01*w01 + v10*w10 + v11*w11;
        }
    }
}

extern "C" void kernel_launch(void* const* d_in, const int* in_sizes, int n_in,
                              void* d_out, int out_size, void* d_ws, size_t ws_size,
                              hipStream_t stream) {
    (void)in_sizes; (void)n_in; (void)d_ws; (void)ws_size; (void)out_size;
    const float* z0 = (const float*)d_in[0];
    const float* z1 = (const float*)d_in[1];
    float* out = (float*)d_out;
    skw_kernel<<<dim3(1024), dim3(256), 0, stream>>>(z0, z1, out);
}